// Round 1
// baseline (88.190 us; speedup 1.0000x reference)
//
#include <hip/hip_runtime.h>

// ElementalGTOLogNormalSkinCutoff on MI355X (gfx950) — round 6
//
// Round-6 vs round-5:
//  * Phase 1 rewritten: M_=64 == wave width, so each wave owns one atom's
//    64 neighbour slots. Species bucketing now uses __ballot + mbcnt
//    (wave-exclusive scan) instead of two rounds of LDS atomics. This
//    removes 2048 serialized LDS atomics/block, 3 of the 4 barriers, and
//    the rP/rQ/rls/rv register arrays that lived across __syncthreads.
//  * __launch_bounds__(320, 5): cap VGPR at ~102 so 4 blocks/CU are
//    resident -> the full 1024-block grid fits in ONE residency pass
//    (4 x 256 CUs), killing the 256-block tail.
//  * Segment loops unrolled x4 (4 independent exp2 chains in flight).
//
// Round-5 NaN fix retained: clamp amp to 1e-30 before log2 (boundary
// neighbours at d ~= 6.0 can give tiny-negative cut under rsqrt error).

#define B_   128
#define N_   128
#define M_   64
#define NG_  20
#define NSP_ 4
#define FPSIZE_ 600
#define APB  16                      // atoms per block (divides N_)
#define BLOCK_THREADS (APB * NG_)    // 320 = 5 waves
#define NWAVE (BLOCK_THREADS / 64)   // 5
#define P1ITER ((APB + NWAVE - 1) / NWAVE)   // 4 wave-rounds cover 16 atoms

__global__ __launch_bounds__(BLOCK_THREADS, 5)
void gto_fp_kernel(const float* __restrict__ coords,   // [B,N,3]
                   const int*   __restrict__ charges,  // [B,N]
                   const int*   __restrict__ counts,   // [B]
                   const int*   __restrict__ neigh,    // [B,N,M]
                   float*       __restrict__ out)      // [B,N,600]
{
    __shared__ float4 sP[APB][M_ + 1];      // c0, c1, c2, ux  (padded row)
    __shared__ float2 sQ[APB][M_ + 1];      // uy, uz          (padded row)
    __shared__ int    s_seg[APB][NSP_ + 1]; // species segment starts, [4]=total

    const int tid  = threadIdx.x;
    const int lane = tid & 63;
    const int wid  = tid >> 6;
    const int blockBase = blockIdx.x * APB;
    const int bidx = blockBase / N_;        // uniform: APB divides N_

    // ---------------- phase 1: one wave == one atom's 64 slots -----------
#pragma unroll
    for (int it = 0; it < P1ITER; ++it) {
        const int la = wid + it * NWAVE;    // bijection onto 0..19; skip >=16
        if (la < APB) {
            const int atom = blockBase + la;
            const int nb = neigh[atom * M_ + lane];
            bool v = (nb >= 0);
            int s = 0;
            float4 P = make_float4(0.f, 0.f, 0.f, 0.f);
            float2 Q = make_float2(0.f, 0.f);
            if (v) {
                const int nidx = bidx * N_ + nb;
                const float dx = coords[atom * 3 + 0] - coords[nidx * 3 + 0];
                const float dy = coords[atom * 3 + 1] - coords[nidx * 3 + 1];
                const float dz = coords[atom * 3 + 2] - coords[nidx * 3 + 2];
                const int   z  = charges[nidx];

                const float d2     = dx * dx + dy * dy + dz * dz;
                const float inv_d  = __builtin_amdgcn_rsqf(d2);
                const float d      = d2 * inv_d;
                const float inv_d2 = inv_d * inv_d;

                const float dsw  = (d - 1.0f) * 0.2f;
                const float dsw2 = dsw * dsw;
                const float cut  = 1.0f - dsw2 * dsw * fmaf(6.0f, dsw2, fmaf(-15.0f, dsw, 10.0f));

                const float sigma2 = __logf(fmaf(2.0f, inv_d2, 1.0f));     // log(1+W/d^2)
                const float mu     = 0.5f * (__logf(d2) - sigma2);         // log(d)-s2/2
                const float amp    = fmaxf(__builtin_amdgcn_rsqf(sigma2) * cut * inv_d2,
                                           1.0e-30f);   // clamp: cut can be ~-1e-7 at d~6

                const float F  = -0.72134752f * __builtin_amdgcn_rcpf(sigma2); // -0.5*log2e/s2
                const float Fm = F * mu;
                const float c0 = F;
                const float c1 = -(Fm + Fm);
                const float c2 = fmaf(Fm, mu, __log2f(amp));

                s = (z == 1) ? 0 : (z - 5);   // {1,6,7,8} -> {0,1,2,3}
                P = make_float4(c0, c1, c2, dx * inv_d);
                Q = make_float2(dy * inv_d, dz * inv_d);
            }
            // wave-wide species bucketing: ballot + exclusive lane scan
            const unsigned long long b0 = __ballot(v && (s == 0));
            const unsigned long long b1 = __ballot(v && (s == 1));
            const unsigned long long b2 = __ballot(v && (s == 2));
            const unsigned long long b3 = __ballot(v && (s == 3));
            const int c0n = __popcll(b0), c1n = __popcll(b1),
                      c2n = __popcll(b2), c3n = __popcll(b3);
            const int o0 = __builtin_amdgcn_mbcnt_hi((unsigned)(b0 >> 32),
                           __builtin_amdgcn_mbcnt_lo((unsigned)b0, 0u));
            const int o1 = __builtin_amdgcn_mbcnt_hi((unsigned)(b1 >> 32),
                           __builtin_amdgcn_mbcnt_lo((unsigned)b1, 0u));
            const int o2 = __builtin_amdgcn_mbcnt_hi((unsigned)(b2 >> 32),
                           __builtin_amdgcn_mbcnt_lo((unsigned)b2, 0u));
            const int o3 = __builtin_amdgcn_mbcnt_hi((unsigned)(b3 >> 32),
                           __builtin_amdgcn_mbcnt_lo((unsigned)b3, 0u));
            int slot = o0;
            slot = (s == 1) ? c0n + o1 : slot;
            slot = (s == 2) ? c0n + c1n + o2 : slot;
            slot = (s == 3) ? c0n + c1n + c2n + o3 : slot;
            if (v) {
                sP[la][slot] = P;
                sQ[la][slot] = Q;
            }
            if (lane == 0) {
                s_seg[la][0] = 0;
                s_seg[la][1] = c0n;
                s_seg[la][2] = c0n + c1n;
                s_seg[la][3] = c0n + c1n + c2n;
                s_seg[la][4] = c0n + c1n + c2n + c3n;
            }
        }
    }
    __syncthreads();

    // ---------------- phase 2: accumulate T, emit outputs ----------------
    const int g  = tid % NG_;
    const int la = tid / NG_;
    const int atom = blockBase + la;
    const int n = atom % N_;

    const float off         = 0.3f * (float)(g + 1);
    const float lo          = __logf(off);            // natural-log space
    const float lo2         = lo * lo;
    const float inv_off_spi = 1.0f / (off * 1.7724538509055159f);

    float T[NSP_][10];
#pragma unroll
    for (int s = 0; s < NSP_; ++s)
#pragma unroll
        for (int a = 0; a < 10; ++a) T[s][a] = 0.0f;

#define BODY(SS, P, Q)                                                        \
    {                                                                         \
        const float rad = __builtin_amdgcn_exp2f(                             \
            fmaf(P.x, lo2, fmaf(P.y, lo, P.z)));                              \
        const float rx = rad * P.w, ry = rad * Q.x, rz = rad * Q.y;           \
        T[SS][0] += rad;                                                      \
        T[SS][1] += rx;  T[SS][2] += ry;  T[SS][3] += rz;                     \
        T[SS][4] = fmaf(rx, P.w, T[SS][4]);                                   \
        T[SS][5] = fmaf(rx, Q.x, T[SS][5]);                                   \
        T[SS][6] = fmaf(ry, Q.x, T[SS][6]);                                   \
        T[SS][7] = fmaf(rx, Q.y, T[SS][7]);                                   \
        T[SS][8] = fmaf(ry, Q.y, T[SS][8]);                                   \
        T[SS][9] = fmaf(rz, Q.y, T[SS][9]);                                   \
    }

#define ACC(SS)                                                               \
    {                                                                         \
        const int e0 = s_seg[la][SS];                                         \
        const int e1 = s_seg[la][SS + 1];                                     \
        int m = e0;                                                           \
        for (; m + 3 < e1; m += 4) {                                          \
            const float4 Pa = sP[la][m];     const float2 Qa = sQ[la][m];     \
            const float4 Pb = sP[la][m + 1]; const float2 Qb = sQ[la][m + 1]; \
            const float4 Pc = sP[la][m + 2]; const float2 Qc = sQ[la][m + 2]; \
            const float4 Pd = sP[la][m + 3]; const float2 Qd = sQ[la][m + 3]; \
            BODY(SS, Pa, Qa)                                                  \
            BODY(SS, Pb, Qb)                                                  \
            BODY(SS, Pc, Qc)                                                  \
            BODY(SS, Pd, Qd)                                                  \
        }                                                                     \
        for (; m < e1; ++m) {                                                 \
            const float4 Pa = sP[la][m]; const float2 Qa = sQ[la][m];         \
            BODY(SS, Pa, Qa)                                                  \
        }                                                                     \
    }
    ACC(0) ACC(1) ACC(2) ACC(3)
#undef ACC
#undef BODY

    // output scale: atom mask * (1/(off*sqrt(pi)))^2  (quadratic in T)
    const float amask = (n < counts[bidx]) ? 1.0f : 0.0f;
    const float scale = amask * inv_off_spi * inv_off_spi;
    float* op = out + atom * FPSIZE_ + g;

    // angw = [1, 1,1,1, 1,2,1,2,2,1]; lw = 1 for all l
#pragma unroll
    for (int l = 0; l < 3; ++l) {
        const int a0 = (l == 0) ? 0 : (l == 1) ? 1 : 4;
        const int a1 = (l == 0) ? 1 : (l == 1) ? 4 : 10;
#pragma unroll
        for (int s = 0; s < NSP_; ++s) {
            float v = 0.0f;
#pragma unroll
            for (int a = a0; a < a1; ++a) {
                const float w = (a == 5 || a == 7 || a == 8) ? 2.0f : 1.0f;
                v = fmaf(w * T[s][a], T[s][a], v);
            }
            op[(l * 10 + s) * NG_] = scale * v;
        }
        int mb = 4;
#pragma unroll
        for (int i = 0; i < NSP_; ++i) {
#pragma unroll
            for (int j = i + 1; j < NSP_; ++j) {
                float v = 0.0f;
#pragma unroll
                for (int a = a0; a < a1; ++a) {
                    const float w = (a == 5 || a == 7 || a == 8) ? 2.0f : 1.0f;
                    v = fmaf(w * T[i][a], T[j][a], v);
                }
                op[(l * 10 + mb) * NG_] = scale * (2.0f * v);
                ++mb;
            }
        }
    }
}

extern "C" void kernel_launch(void* const* d_in, const int* in_sizes, int n_in,
                              void* d_out, int out_size, void* d_ws, size_t ws_size,
                              hipStream_t stream) {
    const float* coords  = (const float*)d_in[0];
    const int*   charges = (const int*)d_in[1];
    const int*   counts  = (const int*)d_in[2];
    const int*   neigh   = (const int*)d_in[3];
    float*       outp    = (float*)d_out;

    const int blocks = (B_ * N_) / APB;   // 1024
    gto_fp_kernel<<<blocks, BLOCK_THREADS, 0, stream>>>(coords, charges, counts, neigh, outp);
}